// Round 12
// baseline (958.312 us; speedup 1.0000x reference)
//
#include <hip/hip_runtime.h>
#include <cstdint>
#include <cstddef>

#define E_N 500000
#define FD 128
#define TD 100
#define OD 128
#define NT 4
#define IND 228   // FD + TD
#define KP 256    // K padded to MFMA multiple
#define GRID1 1024

// workspace: only the converted W
static constexpr size_t WBF_OFF  = 0;                                   // bf16[NT][OD][KP] = 262,144
static constexpr size_t WS_NEED  = (size_t)NT * OD * KP * 2;

typedef __attribute__((ext_vector_type(8))) short short8;
typedef __attribute__((ext_vector_type(4))) float f32x4;

__device__ __forceinline__ unsigned short f2bf(float x) {
  union { float f; unsigned u; } v; v.f = x;
  unsigned r = v.u + 0x7fff + ((v.u >> 16) & 1);   // RNE, inputs are finite
  return (unsigned short)(r >> 16);
}

// swizzled byte offset into the A tile: row r (0..63), k elem (0..255), bf16.
__device__ __forceinline__ int a_off(int r, int k) {
  return ((r << 9) + (k << 1)) ^ ((r & 7) << 4);
}

// W [NT][IND][OD] f32 -> Wbf [NT][OD][KP] bf16 (N-major, K zero-padded beyond 228)
__global__ void wconv_kernel(const float* __restrict__ W, unsigned short* __restrict__ Wbf) {
  int row = blockIdx.x * 4 + (threadIdx.x >> 6);   // row = t*OD + n, 0..511
  int t = row >> 7, n = row & 127;
  int k0 = (threadIdx.x & 63) << 2;
  ushort4 o;
  float v0 = (k0 + 0 < IND) ? W[((size_t)t * IND + k0 + 0) * OD + n] : 0.f;
  float v1 = (k0 + 1 < IND) ? W[((size_t)t * IND + k0 + 1) * OD + n] : 0.f;
  float v2 = (k0 + 2 < IND) ? W[((size_t)t * IND + k0 + 2) * OD + n] : 0.f;
  float v3 = (k0 + 3 < IND) ? W[((size_t)t * IND + k0 + 3) * OD + n] : 0.f;
  o.x = f2bf(v0); o.y = f2bf(v1); o.z = f2bf(v2); o.w = f2bf(v3);
  *(ushort4*)(Wbf + ((size_t)row << 8) + k0) = o;
}

// Main kernel: STREAMING both ways. Edges in original order (feats read and
// out write are sequential full-line streams; the r9 bucketed gather/scatter
// was pattern-limited at ~2.2 TB/s). Each 64-edge tile is multiplied by all 4
// per-type W (4x MFMA ~62us chip-wide, hides under ~90us of streaming memory).
// Row selection WITHOUT fin regs / LDS epilogue: in pass t, lanes whose row
// type == t store their acc directly (each row stored exactly once; a tile's
// stores cover one contiguous 32KB window -> L2 write-combines cleanly).
// Register discipline (r10 lesson): rt OUTER unrolled (A-frags read once per
// rt), type loop INNER '#pragma unroll 1' so ONE bfr set (64 VGPR) recycles.
__global__ __launch_bounds__(256) void gemm_kernel(
    const float* __restrict__ feats, const float* __restrict__ ts,
    const int* __restrict__ types, const float* __restrict__ freqs,
    const float* __restrict__ b, const float* __restrict__ temb,
    const unsigned short* __restrict__ Wbf, float* __restrict__ out) {
  __shared__ __align__(16) char smA[64 * 512];      // A bf16 [64][256], XOR-swizzled
  __shared__ __align__(16) float sfreq[NT * 128];   // per-type freqs, zero-padded
  __shared__ __align__(16) float sbias[NT * 128];   // b + temb

  const int ntiles = (E_N + 63) >> 6;
  const int chunk = (ntiles + GRID1 - 1) / GRID1;
  const int t0 = blockIdx.x * chunk;
  const int t1 = min(t0 + chunk, ntiles);
  if (t0 >= t1) return;

  const int tid = threadIdx.x;
  const int wid = tid >> 6, lane = tid & 63;
  const int bl = lane & 15, bh = lane >> 4;
  const int r = tid >> 2, part = tid & 3;   // 4 threads per A-row; part = 32-elem window

  for (int i = tid; i < NT * 128; i += 256) {
    int ty = i >> 7, d = i & 127;
    sfreq[i] = (d < TD) ? freqs[ty * TD + d] : 0.f;
    sbias[i] = b[i] + temb[i];
  }

  auto stage = [&](const float4* p, float tvv, int tr) {
    union { unsigned short s[32]; uint4 v4[4]; } pk;
    union { unsigned short s[32]; uint4 v4[4]; } tk;
    #pragma unroll
    for (int c = 0; c < 8; ++c) {
      pk.s[4 * c + 0] = f2bf(p[c].x); pk.s[4 * c + 1] = f2bf(p[c].y);
      pk.s[4 * c + 2] = f2bf(p[c].z); pk.s[4 * c + 3] = f2bf(p[c].w);
    }
    #pragma unroll
    for (int m = 0; m < 8; ++m) {
      float4 fq = *(const float4*)&sfreq[tr * 128 + part * 32 + 4 * m];
      tk.s[4 * m + 0] = f2bf(__cosf(tvv * fq.x));
      tk.s[4 * m + 1] = f2bf(__cosf(tvv * fq.y));
      tk.s[4 * m + 2] = f2bf(__cosf(tvv * fq.z));
      tk.s[4 * m + 3] = f2bf(__cosf(tvv * fq.w));
    }
    #pragma unroll
    for (int j = 0; j < 4; ++j)
      *(uint4*)(smA + a_off(r, part * 32 + 8 * j)) = pk.v4[j];
    #pragma unroll
    for (int j = 0; j < 4; ++j)
      *(uint4*)(smA + a_off(r, FD + part * 32 + 8 * j)) = tk.v4[j];
  };

  // ---- prologue: tile t0 (streaming, no indirection) ----
  float4 pf[8];
  float tv_cur = 0.f; int tr_cur = 0; bool v_cur = false;
  {
    int e = t0 * 64 + r;
    v_cur = (e < E_N);
    if (v_cur) {
      tv_cur = ts[e]; tr_cur = types[e];
      const float4* src = (const float4*)(feats + (size_t)e * FD + part * 32);
      #pragma unroll
      for (int c = 0; c < 8; ++c) pf[c] = src[c];
    }
  }
  __syncthreads();                 // sfreq/sbias ready
  if (v_cur) stage(pf, tv_cur, tr_cur);

  for (int tt = t0; tt < t1; ++tt) {
    const bool last = (tt == t1 - 1);
    __syncthreads();               // A(tt) ready

    // streaming prefetch of tile tt+1 (rides under the 4 MFMA passes)
    float tv_b = 0.f; int tr_b = 0; bool v_b = false;
    if (!last) {
      int e = (tt + 1) * 64 + r;
      v_b = (e < E_N);
      if (v_b) {
        tv_b = ts[e]; tr_b = types[e];
        const float4* src = (const float4*)(feats + (size_t)e * FD + part * 32);
        #pragma unroll
        for (int c = 0; c < 8; ++c) pf[c] = src[c];
      }
    }

    // rt OUTER (A-frags read once per rt, 32 VGPR, reused across passes);
    // type loop INNER, unroll 1 (single bfr set recycled -> no VGPR blowup).
    #pragma unroll
    for (int rt = 0; rt < 4; ++rt) {
      const int row = tt * 64 + rt * 16 + bl;
      const int tp = (row < E_N) ? types[row] : -1;
      short8 av[8];
      #pragma unroll
      for (int k = 0; k < 8; ++k)
        av[k] = *(const short8*)(smA + a_off(rt * 16 + bl, k * 32 + bh * 8));
      float* dst = out + (size_t)row * OD + wid * 32 + bh * 4;

      #pragma unroll 1
      for (int t = 0; t < NT; ++t) {
        short8 bfr[8][2];
        #pragma unroll
        for (int n = 0; n < 2; ++n) {
          const unsigned short* bp =
              Wbf + (((size_t)t * OD + wid * 32 + n * 16 + bl) << 8) + (bh << 3);
          #pragma unroll
          for (int k = 0; k < 8; ++k) bfr[k][n] = *(const short8*)(bp + k * 32);
        }
        f32x4 a0 = *(const f32x4*)&sbias[t * 128 + wid * 32 + bh * 4];
        f32x4 a1 = *(const f32x4*)&sbias[t * 128 + wid * 32 + 16 + bh * 4];
        __builtin_amdgcn_s_setprio(1);
        #pragma unroll
        for (int k = 0; k < 8; ++k) {
          a0 = __builtin_amdgcn_mfma_f32_16x16x32_bf16(bfr[k][0], av[k], a0, 0, 0, 0);
          a1 = __builtin_amdgcn_mfma_f32_16x16x32_bf16(bfr[k][1], av[k], a1, 0, 0, 0);
        }
        __builtin_amdgcn_s_setprio(0);
        if (tp == t) {               // exactly one pass stores each valid row
          *(f32x4*)(dst) = a0;
          *(f32x4*)(dst + 16) = a1;
        }
      }
    }
    __syncthreads();               // A consumed (drains pf + stores compactly)

    if (!last && v_b) stage(pf, tv_b, tr_b);
    v_cur = v_b; tv_cur = tv_b; tr_cur = tr_b;
  }
}

// correctness fallback if ws is too small (fp32 vector path)
__global__ void naive_kernel(const float* __restrict__ feats, const float* __restrict__ ts,
                             const int* __restrict__ types, const float* __restrict__ W,
                             const float* __restrict__ b, const float* __restrict__ temb,
                             const float* __restrict__ freqs, float* __restrict__ out) {
  __shared__ float comb[IND];
  int e = blockIdx.x;
  int t = types[e];
  int tid = threadIdx.x;  // 128 threads
  comb[tid] = feats[(size_t)e * FD + tid];
  if (tid < TD) comb[FD + tid] = __cosf(ts[e] * freqs[t * TD + tid]);
  __syncthreads();
  float acc = b[t * OD + tid] + temb[t * OD + tid];
  for (int k = 0; k < IND; ++k) acc += comb[k] * W[((size_t)t * IND + k) * OD + tid];
  out[(size_t)e * OD + tid] = acc;
}

extern "C" void kernel_launch(void* const* d_in, const int* in_sizes, int n_in,
                              void* d_out, int out_size, void* d_ws, size_t ws_size,
                              hipStream_t stream) {
  const float* feats = (const float*)d_in[0];
  const float* ts    = (const float*)d_in[1];
  const int*   types = (const int*)d_in[2];
  const float* W     = (const float*)d_in[3];
  const float* bb    = (const float*)d_in[4];
  const float* temb  = (const float*)d_in[5];
  const float* freqs = (const float*)d_in[6];
  float* out = (float*)d_out;

  if (ws_size < WS_NEED) {
    naive_kernel<<<E_N, 128, 0, stream>>>(feats, ts, types, W, bb, temb, freqs, out);
    return;
  }

  unsigned short* Wbf = (unsigned short*)((char*)d_ws + WBF_OFF);
  wconv_kernel<<<(NT * OD) / 4, 256, 0, stream>>>(W, Wbf);
  gemm_kernel<<<GRID1, 256, 0, stream>>>(feats, ts, types, freqs, bb, temb, Wbf, out);
}

// Round 13
// 240.123 us; speedup vs baseline: 3.9909x; 3.9909x over previous
//
#include <hip/hip_runtime.h>
#include <cstdint>
#include <cstddef>

#define E_N 500000
#define FD 128
#define TD 100
#define OD 128
#define NT 4
#define IND 228   // FD + TD
#define KP 256    // K padded to MFMA multiple
#define GRID1 1024
#define TPB 512   // 8 waves; wave w owns out-cols [w*16, w*16+16)

// workspace: only the converted W
static constexpr size_t WS_NEED = (size_t)NT * OD * KP * 2;   // 262,144 B

typedef __attribute__((ext_vector_type(8))) short short8;
typedef __attribute__((ext_vector_type(4))) float f32x4;

__device__ __forceinline__ unsigned short f2bf(float x) {
  union { float f; unsigned u; } v; v.f = x;
  unsigned r = v.u + 0x7fff + ((v.u >> 16) & 1);   // RNE, inputs are finite
  return (unsigned short)(r >> 16);
}

// swizzled byte offset into the A tile: row r (0..63), k elem (0..255), bf16.
__device__ __forceinline__ int a_off(int r, int k) {
  return ((r << 9) + (k << 1)) ^ ((r & 7) << 4);
}

// W [NT][IND][OD] f32 -> Wbf [NT][OD][KP] bf16 (N-major, K zero-padded beyond 228)
__global__ void wconv_kernel(const float* __restrict__ W, unsigned short* __restrict__ Wbf) {
  int row = blockIdx.x * 4 + (threadIdx.x >> 6);   // row = t*OD + n, 0..511
  int t = row >> 7, n = row & 127;
  int k0 = (threadIdx.x & 63) << 2;
  ushort4 o;
  float v0 = (k0 + 0 < IND) ? W[((size_t)t * IND + k0 + 0) * OD + n] : 0.f;
  float v1 = (k0 + 1 < IND) ? W[((size_t)t * IND + k0 + 1) * OD + n] : 0.f;
  float v2 = (k0 + 2 < IND) ? W[((size_t)t * IND + k0 + 2) * OD + n] : 0.f;
  float v3 = (k0 + 3 < IND) ? W[((size_t)t * IND + k0 + 3) * OD + n] : 0.f;
  o.x = f2bf(v0); o.y = f2bf(v1); o.z = f2bf(v2); o.w = f2bf(v3);
  *(ushort4*)(Wbf + ((size_t)row << 8) + k0) = o;
}

// Main kernel: STREAM tiles in original order (sequential feats read + out
// write). Per tile, wave 0 builds a type-grouped row permutation (ballot
// compaction, padded to 16); MFMA runs per type-uniform 16-row subtile with
// A-rows gathered inside LDS via the permutation. All 4 types' W fragments
// live in 4 NAMED register sets (w*16 cols per wave); runtime type dispatch
// via readfirstlane + uniform switch (no runtime reg indexing, no W reloads).
__global__ __launch_bounds__(512) void gemm_kernel(
    const float* __restrict__ feats, const float* __restrict__ ts,
    const int* __restrict__ types, const float* __restrict__ freqs,
    const float* __restrict__ b, const float* __restrict__ temb,
    const unsigned short* __restrict__ Wbf, float* __restrict__ out) {
  __shared__ __align__(16) char smA[64 * 512];      // A bf16 [64][256], XOR-swizzled
  __shared__ __align__(16) float sfreq[NT * 128];   // per-type freqs, zero-padded
  __shared__ __align__(16) float sbias[NT * 128];   // b + temb
  __shared__ int perm[128];                          // type-grouped local rows, -1 pad
  __shared__ int subty[8];                           // subtile -> type (<=7 subtiles)
  __shared__ int snsub;

  const int ntiles = (E_N + 63) >> 6;
  const int chunk = (ntiles + GRID1 - 1) / GRID1;
  const int t0 = blockIdx.x * chunk;
  const int t1 = min(t0 + chunk, ntiles);
  if (t0 >= t1) return;

  const int tid = threadIdx.x;
  const int w = tid >> 6, lane = tid & 63;
  const int bl = lane & 15, bh = lane >> 4;
  const int r = tid >> 3, part = tid & 7;   // 8 threads per A-row; 32-elem windows

  // W fragments for all 4 types, this wave's 16 cols (named sets: rule #20)
  short8 bf0[8], bf1[8], bf2[8], bf3[8];
  {
    const unsigned short* p0 = Wbf + (((size_t)0 * OD + w * 16 + bl) << 8) + (bh << 3);
    const unsigned short* p1 = Wbf + (((size_t)1 * OD + w * 16 + bl) << 8) + (bh << 3);
    const unsigned short* p2 = Wbf + (((size_t)2 * OD + w * 16 + bl) << 8) + (bh << 3);
    const unsigned short* p3 = Wbf + (((size_t)3 * OD + w * 16 + bl) << 8) + (bh << 3);
    #pragma unroll
    for (int k = 0; k < 8; ++k) {
      bf0[k] = *(const short8*)(p0 + k * 32);
      bf1[k] = *(const short8*)(p1 + k * 32);
      bf2[k] = *(const short8*)(p2 + k * 32);
      bf3[k] = *(const short8*)(p3 + k * 32);
    }
  }

  for (int i = tid; i < NT * 128; i += TPB) {
    int ty = i >> 7, d = i & 127;
    sfreq[i] = (d < TD) ? freqs[ty * TD + d] : 0.f;
    sbias[i] = b[i] + temb[i];
  }

  // stage this thread's 32-elem window of row r (parts 0-3 feats, 4-7 time)
  auto stage = [&](const float4* p, float tvv, int tr, bool valid) {
    if (!valid) return;   // rows >= E_N excluded via perm; stale LDS harmless
    if (part < 4) {
      union { unsigned short s[32]; uint4 v4[4]; } pk;
      #pragma unroll
      for (int c = 0; c < 8; ++c) {
        pk.s[4 * c + 0] = f2bf(p[c].x); pk.s[4 * c + 1] = f2bf(p[c].y);
        pk.s[4 * c + 2] = f2bf(p[c].z); pk.s[4 * c + 3] = f2bf(p[c].w);
      }
      #pragma unroll
      for (int j = 0; j < 4; ++j)
        *(uint4*)(smA + a_off(r, part * 32 + 8 * j)) = pk.v4[j];
    } else {
      const int p4 = part - 4;
      union { unsigned short s[32]; uint4 v4[4]; } tk;
      #pragma unroll
      for (int m = 0; m < 8; ++m) {
        float4 fq = *(const float4*)&sfreq[tr * 128 + p4 * 32 + 4 * m];
        tk.s[4 * m + 0] = f2bf(__cosf(tvv * fq.x));
        tk.s[4 * m + 1] = f2bf(__cosf(tvv * fq.y));
        tk.s[4 * m + 2] = f2bf(__cosf(tvv * fq.z));
        tk.s[4 * m + 3] = f2bf(__cosf(tvv * fq.w));
      }
      #pragma unroll
      for (int j = 0; j < 4; ++j)
        *(uint4*)(smA + a_off(r, FD + p4 * 32 + 8 * j)) = tk.v4[j];
    }
  };

  // wave 0: ballot-compact rows by type into perm (padded groups of 16)
  auto compact = [&](int tyrow) {
    if (tid < 64) {
      perm[tid] = -1; perm[64 + tid] = -1;
      const unsigned long long lt = (1ull << tid) - 1ull;
      int c[4]; int pb = 0; int slot = -1;
      int pbs[4];
      #pragma unroll
      for (int q = 0; q < 4; ++q) {
        unsigned long long m = __ballot(tyrow == q);
        c[q] = (int)__popcll(m);
        pbs[q] = pb;
        if (tyrow == q) slot = pb + (int)__popcll(m & lt);
        pb += (c[q] + 15) & ~15;
      }
      if (slot >= 0) perm[slot] = tid;
      if (tid == 0) {
        int s = 0;
        for (int q = 0; q < 4; ++q)
          for (int g = 0; g < (c[q] + 15) / 16; ++g) subty[s++] = q;
        snsub = s;
      }
    }
  };

  // ---- prologue: tile t0 ----
  float4 pf[8];
  float tv_cur = 0.f; int tr_cur = 0; bool v_cur = false; int tyrow_cur = -1;
  {
    int e = t0 * 64 + r;
    v_cur = (e < E_N);
    if (v_cur) {
      if (part < 4) {
        const float4* src = (const float4*)(feats + (size_t)e * FD + part * 32);
        #pragma unroll
        for (int c = 0; c < 8; ++c) pf[c] = src[c];
      } else {
        tv_cur = ts[e]; tr_cur = types[e];
      }
    }
    if (tid < 64) {
      int e2 = t0 * 64 + tid;
      tyrow_cur = (e2 < E_N) ? types[e2] : -1;
    }
  }
  __syncthreads();                 // sfreq/sbias ready
  stage(pf, tv_cur, tr_cur, v_cur);
  compact(tyrow_cur);

  for (int tt = t0; tt < t1; ++tt) {
    const bool last = (tt == t1 - 1);
    __syncthreads();               // A(tt) + perm(tt) ready

    // streaming prefetch of tile tt+1 (rides under the subtile MFMAs)
    float tv_b = 0.f; int tr_b = 0; bool v_b = false; int tyrow_b = -1;
    if (!last) {
      int e = (tt + 1) * 64 + r;
      v_b = (e < E_N);
      if (v_b) {
        if (part < 4) {
          const float4* src = (const float4*)(feats + (size_t)e * FD + part * 32);
          #pragma unroll
          for (int c = 0; c < 8; ++c) pf[c] = src[c];
        } else {
          tv_b = ts[e]; tr_b = types[e];
        }
      }
      if (tid < 64) {
        int e2 = (tt + 1) * 64 + tid;
        tyrow_b = (e2 < E_N) ? types[e2] : -1;
      }
    }

    // ---- per type-uniform subtile: LDS row-gather + MFMA + direct store ----
    const int ns = snsub;
    for (int s = 0; s < ns; ++s) {
      const int rl = perm[s * 16 + bl];
      const int tsu = __builtin_amdgcn_readfirstlane(subty[s]);
      const int rowa = (rl < 0) ? 0 : rl;
      short8 av[8];
      #pragma unroll
      for (int k = 0; k < 8; ++k)
        av[k] = *(const short8*)(smA + a_off(rowa, k * 32 + bh * 8));
      f32x4 a0 = *(const f32x4*)&sbias[tsu * 128 + w * 16 + bh * 4];
      __builtin_amdgcn_s_setprio(1);
      switch (tsu) {
        case 0:
          #pragma unroll
          for (int k = 0; k < 8; ++k) a0 = __builtin_amdgcn_mfma_f32_16x16x32_bf16(bf0[k], av[k], a0, 0, 0, 0);
          break;
        case 1:
          #pragma unroll
          for (int k = 0; k < 8; ++k) a0 = __builtin_amdgcn_mfma_f32_16x16x32_bf16(bf1[k], av[k], a0, 0, 0, 0);
          break;
        case 2:
          #pragma unroll
          for (int k = 0; k < 8; ++k) a0 = __builtin_amdgcn_mfma_f32_16x16x32_bf16(bf2[k], av[k], a0, 0, 0, 0);
          break;
        default:
          #pragma unroll
          for (int k = 0; k < 8; ++k) a0 = __builtin_amdgcn_mfma_f32_16x16x32_bf16(bf3[k], av[k], a0, 0, 0, 0);
          break;
      }
      __builtin_amdgcn_s_setprio(0);
      if (rl >= 0) {   // each valid row stored exactly once; tile rows contiguous
        float* dst = out + (size_t)(tt * 64 + rl) * OD + w * 16 + bh * 4;
        *(f32x4*)dst = a0;
      }
    }
    __syncthreads();               // A/perm consumed; region reusable

    if (!last) {
      stage(pf, tv_b, tr_b, v_b);
      compact(tyrow_b);
      v_cur = v_b; tv_cur = tv_b; tr_cur = tr_b; tyrow_cur = tyrow_b;
    }
  }
}

// correctness fallback if ws is too small (fp32 vector path)
__global__ void naive_kernel(const float* __restrict__ feats, const float* __restrict__ ts,
                             const int* __restrict__ types, const float* __restrict__ W,
                             const float* __restrict__ b, const float* __restrict__ temb,
                             const float* __restrict__ freqs, float* __restrict__ out) {
  __shared__ float comb[IND];
  int e = blockIdx.x;
  int t = types[e];
  int tid = threadIdx.x;  // 128 threads
  comb[tid] = feats[(size_t)e * FD + tid];
  if (tid < TD) comb[FD + tid] = __cosf(ts[e] * freqs[t * TD + tid]);
  __syncthreads();
  float acc = b[t * OD + tid] + temb[t * OD + tid];
  for (int k = 0; k < IND; ++k) acc += comb[k] * W[((size_t)t * IND + k) * OD + tid];
  out[(size_t)e * OD + tid] = acc;
}

extern "C" void kernel_launch(void* const* d_in, const int* in_sizes, int n_in,
                              void* d_out, int out_size, void* d_ws, size_t ws_size,
                              hipStream_t stream) {
  const float* feats = (const float*)d_in[0];
  const float* ts    = (const float*)d_in[1];
  const int*   types = (const int*)d_in[2];
  const float* W     = (const float*)d_in[3];
  const float* bb    = (const float*)d_in[4];
  const float* temb  = (const float*)d_in[5];
  const float* freqs = (const float*)d_in[6];
  float* out = (float*)d_out;

  if (ws_size < WS_NEED) {
    naive_kernel<<<E_N, 128, 0, stream>>>(feats, ts, types, W, bb, temb, freqs, out);
    return;
  }

  unsigned short* Wbf = (unsigned short*)d_ws;
  wconv_kernel<<<(NT * OD) / 4, 256, 0, stream>>>(W, Wbf);
  gemm_kernel<<<GRID1, TPB, 0, stream>>>(feats, ts, types, freqs, bb, temb, Wbf, out);
}